// Round 1
// baseline (970.527 us; speedup 1.0000x reference)
//
#include <hip/hip_runtime.h>
#include <math.h>

#define D 64

// ---------------- degree / norm precompute ----------------

__global__ void k_init_deg(float* deg, int n) {
    int i = blockIdx.x * 256 + threadIdx.x;
    if (i < n) deg[i] = 1.0f;  // self-loop weight
}

__global__ void k_deg_accum(const int* __restrict__ col, const float* __restrict__ ew,
                            float* deg, int E) {
    int e = blockIdx.x * 256 + threadIdx.x;
    if (e < E) atomicAdd(&deg[col[e]], ew[e]);
}

__global__ void k_dinv(float* dinv, float* dinv2, int n) {
    int i = blockIdx.x * 256 + threadIdx.x;
    if (i < n) {
        float d = dinv[i];           // deg (>= 1 always)
        dinv[i]  = rsqrtf(d);
        dinv2[i] = 1.0f / d;         // self-loop norm: dinv[i]*1*dinv[i]
    }
}

__global__ void k_norm(const int* __restrict__ row, const int* __restrict__ col,
                       const float* __restrict__ ew, const float* __restrict__ dinv,
                       float* __restrict__ nrm, int E) {
    int e = blockIdx.x * 256 + threadIdx.x;
    if (e < E) nrm[e] = dinv[row[e]] * ew[e] * dinv[col[e]];
}

// ---------------- dense matmul: Y = act(X) @ W, X:[n,64] W:[64,64] ----------------
// block 256 = 4 waves; block tile = 16 rows; each thread: 4 rows x 1 col.

__global__ void k_matmul(const float* __restrict__ X, const float* __restrict__ W,
                         float* __restrict__ Y, int n, int relu_in) {
    __shared__ float ws[64][64];
    __shared__ float xs[16][64];
    int tid = threadIdx.x;
    int c  = tid & 63;
    int rq = tid >> 6;  // 0..3

    for (int i = tid; i < 64 * 64; i += 256) ws[i >> 6][i & 63] = W[i];

    int ntiles = (n + 15) >> 4;
    for (int t = blockIdx.x; t < ntiles; t += gridDim.x) {
        __syncthreads();  // W ready (1st iter) + xs no longer read (later iters)
        int base = t * 16;
        for (int i = tid; i < 16 * 64; i += 256) {
            int rr = i >> 6, kk = i & 63;
            int gr = base + rr;
            float v = (gr < n) ? X[gr * 64 + kk] : 0.0f;
            if (relu_in) v = fmaxf(v, 0.0f);
            xs[rr][kk] = v;
        }
        __syncthreads();
        float a0 = 0.f, a1 = 0.f, a2 = 0.f, a3 = 0.f;
        int r0 = rq * 4;
#pragma unroll
        for (int k = 0; k < 64; ++k) {
            float w = ws[k][c];      // lanes stride-1 -> 2-way bank alias (free)
            a0 += xs[r0 + 0][k] * w; // broadcasts
            a1 += xs[r0 + 1][k] * w;
            a2 += xs[r0 + 2][k] * w;
            a3 += xs[r0 + 3][k] * w;
        }
        int gr = base + r0;
        if (gr + 0 < n) Y[(gr + 0) * 64 + c] = a0;
        if (gr + 1 < n) Y[(gr + 1) * 64 + c] = a1;
        if (gr + 2 < n) Y[(gr + 2) * 64 + c] = a2;
        if (gr + 3 < n) Y[(gr + 3) * 64 + c] = a3;
    }
}

// ---------------- acc init: acc[i][f] = dinv2[i]*xw[i][f] + b[f] ----------------

__global__ void k_init_acc(const float* __restrict__ xw, const float* __restrict__ dinv2,
                           const float* __restrict__ b, float* __restrict__ acc, int n) {
    int idx = blockIdx.x * 256 + threadIdx.x;
    if (idx < n * D) {
        int i = idx >> 6, f = idx & 63;
        acc[idx] = dinv2[i] * xw[idx] + b[f];
    }
}

// ---------------- edge scatter: acc[col] += norm * xw[row], one wave/edge ----------------

__global__ void k_scatter(const int* __restrict__ row, const int* __restrict__ col,
                          const float* __restrict__ nrm, const float* __restrict__ xw,
                          float* __restrict__ acc, int E) {
    int idx = blockIdx.x * 256 + threadIdx.x;
    if (idx < E * D) {
        int e = idx >> 6, f = idx & 63;
        atomicAdd(&acc[col[e] * 64 + f], nrm[e] * xw[row[e] * 64 + f]);
    }
}

// ---------------- fused head: relu -> @Wm1+bm1 -> relu -> @Wm2+bm2 -> sigmoid ----------------
// block 256 = 4 waves, 1 node per wave, lane = feature.

__global__ void k_final(const float* __restrict__ acc2,
                        const float* __restrict__ Wm1, const float* __restrict__ bm1,
                        const float* __restrict__ Wm2, const float* __restrict__ bm2,
                        float* __restrict__ out, int n) {
    __shared__ float w1[64][64];
    __shared__ float w2[64][16];
    __shared__ float sb1[64];
    __shared__ float sb2[16];
    __shared__ float h2s[4][64];
    __shared__ float h3s[4][64];
    int tid = threadIdx.x;
    for (int i = tid; i < 64 * 64; i += 256) w1[i >> 6][i & 63] = Wm1[i];
    for (int i = tid; i < 64 * 16; i += 256) w2[i >> 4][i & 15] = Wm2[i];
    if (tid < 64) sb1[tid] = bm1[tid];
    if (tid < 16) sb2[tid] = bm2[tid];

    int w = tid >> 6, lane = tid & 63;
    int ngrp = (n + 3) >> 2;
    for (int g = blockIdx.x; g < ngrp; g += gridDim.x) {
        int node = g * 4 + w;
        __syncthreads();  // weights ready (1st iter) + h2s/h3s free (later)
        if (node < n) h2s[w][lane] = fmaxf(acc2[node * 64 + lane], 0.0f);
        __syncthreads();
        float s = sb1[lane];
#pragma unroll
        for (int k = 0; k < 64; ++k) s += h2s[w][k] * w1[k][lane];
        h3s[w][lane] = fmaxf(s, 0.0f);
        __syncthreads();
        if (lane < 16 && node < n) {
            float s2 = sb2[lane];
#pragma unroll
            for (int k = 0; k < 64; ++k) s2 += h3s[w][k] * w2[k][lane];
            out[node * 16 + lane] = 1.0f / (1.0f + expf(-s2));
        }
    }
}

// ---------------- launch ----------------

extern "C" void kernel_launch(void* const* d_in, const int* in_sizes, int n_in,
                              void* d_out, int out_size, void* d_ws, size_t ws_size,
                              hipStream_t stream) {
    const float* x   = (const float*)d_in[0];
    const int*   ei  = (const int*)d_in[1];
    const float* ew  = (const float*)d_in[2];
    const float* W1  = (const float*)d_in[3];
    const float* b1  = (const float*)d_in[4];
    const float* W2  = (const float*)d_in[5];
    const float* b2  = (const float*)d_in[6];
    const float* Wm1 = (const float*)d_in[7];
    const float* bm1 = (const float*)d_in[8];
    const float* Wm2 = (const float*)d_in[9];
    const float* bm2 = (const float*)d_in[10];

    int n = in_sizes[0] / D;     // 50000
    int E = in_sizes[1] / 2;     // 800000
    const int* row = ei;
    const int* col = ei + E;

    float* ws    = (float*)d_ws;
    float* dinv  = ws;               // n   (holds deg first)
    float* dinv2 = dinv + n;         // n
    float* nrm   = dinv2 + n;        // E
    float* xw    = nrm + E;          // n*64
    float* acc   = xw + (size_t)n * D; // n*64
    float* out   = (float*)d_out;

    int gN  = (n + 255) / 256;
    int gE  = (E + 255) / 256;
    int gND = (n * D + 255) / 256;
    int gED = (E * D + 255) / 256;

    // norm precompute (shared by both conv layers)
    k_init_deg<<<gN, 256, 0, stream>>>(dinv, n);
    k_deg_accum<<<gE, 256, 0, stream>>>(col, ew, dinv, E);
    k_dinv<<<gN, 256, 0, stream>>>(dinv, dinv2, n);
    k_norm<<<gE, 256, 0, stream>>>(row, col, ew, dinv, nrm, E);

    // conv layer 1
    k_matmul<<<1024, 256, 0, stream>>>(x, W1, xw, n, 0);
    k_init_acc<<<gND, 256, 0, stream>>>(xw, dinv2, b1, acc, n);
    k_scatter<<<gED, 256, 0, stream>>>(row, col, nrm, xw, acc, E);

    // conv layer 2 (relu fused into matmul input read)
    k_matmul<<<1024, 256, 0, stream>>>(acc, W2, xw, n, 1);
    k_init_acc<<<gND, 256, 0, stream>>>(xw, dinv2, b2, acc, n);
    k_scatter<<<gED, 256, 0, stream>>>(row, col, nrm, xw, acc, E);

    // fused MLP head + sigmoid
    k_final<<<2048, 256, 0, stream>>>(acc, Wm1, bm1, Wm2, bm2, out, n);
}

// Round 2
// 807.304 us; speedup vs baseline: 1.2022x; 1.2022x over previous
//
#include <hip/hip_runtime.h>
#include <math.h>

#define D 64

// ---------------- init: deg = 1.0 (self-loop), cnt = 0 ----------------

__global__ void k_init(float* deg, int* cnt, int n) {
    int i = blockIdx.x * 256 + threadIdx.x;
    if (i < n) { deg[i] = 1.0f; cnt[i] = 0; }
}

// ---------------- per-edge: weighted in-degree + integer in-degree ----------------

__global__ void k_count(const int* __restrict__ col, const float* __restrict__ ew,
                        float* deg, int* cnt, int E) {
    int e = blockIdx.x * 256 + threadIdx.x;
    if (e < E) {
        int c = col[e];
        atomicAdd(&deg[c], ew[e]);
        atomicAdd(&cnt[c], 1);
    }
}

// ---------------- dinv = rsqrt(deg), dinv2 = 1/deg (self-loop norm) ----------------

__global__ void k_dinv(float* deg, float* dinv2, int n) {
    int i = blockIdx.x * 256 + threadIdx.x;
    if (i < n) {
        float d = deg[i];            // >= 1 always
        deg[i]   = rsqrtf(d);        // becomes dinv
        dinv2[i] = 1.0f / d;
    }
}

// ---------------- exclusive scan of cnt -> rowptr (single block, 1024 thr) ----------------

__global__ void k_scan(const int* __restrict__ cnt, int* __restrict__ rowptr, int n) {
    __shared__ int sums[1024];
    int t = threadIdx.x;
    int chunk = (n + 1023) >> 10;
    int beg = t * chunk;
    int end = beg + chunk; if (end > n) end = n;
    int s = 0;
    for (int i = beg; i < end; ++i) s += cnt[i];
    int v = s;
    sums[t] = v;
    __syncthreads();
    for (int off = 1; off < 1024; off <<= 1) {
        int u = (t >= off) ? sums[t - off] : 0;
        __syncthreads();
        v += u;
        sums[t] = v;
        __syncthreads();
    }
    int run = v - s;  // exclusive prefix of this chunk
    for (int i = beg; i < end; ++i) {
        rowptr[i] = run;
        run += cnt[i];
    }
    // rowptr[n] never needed: after the fill kernel, rowptr[c] = end of segment c.
}

// ---------------- CSR fill: bucket edges by destination ----------------
// Uses rowptr itself as the cursor: post-fill, segment c = [rowptr[c-1], rowptr[c]).

__global__ void k_csr_fill(const int* __restrict__ row, const int* __restrict__ col,
                           const float* __restrict__ ew, const float* __restrict__ dinv,
                           int* rowptr, int2* __restrict__ edges, int E) {
    int e = blockIdx.x * 256 + threadIdx.x;
    if (e < E) {
        int r = row[e], c = col[e];
        float w = dinv[r] * ew[e] * dinv[c];
        int p = atomicAdd(&rowptr[c], 1);
        edges[p] = make_int2(r, __float_as_int(w));
    }
}

// ---------------- dense matmul: Y = act(X) @ W, X:[n,64] W:[64,64] ----------------

__global__ void k_matmul(const float* __restrict__ X, const float* __restrict__ W,
                         float* __restrict__ Y, int n, int relu_in) {
    __shared__ float ws[64][64];
    __shared__ float xs[16][64];
    int tid = threadIdx.x;
    int c  = tid & 63;
    int rq = tid >> 6;  // 0..3

    for (int i = tid; i < 64 * 64; i += 256) ws[i >> 6][i & 63] = W[i];

    int ntiles = (n + 15) >> 4;
    for (int t = blockIdx.x; t < ntiles; t += gridDim.x) {
        __syncthreads();
        int base = t * 16;
        for (int i = tid; i < 16 * 64; i += 256) {
            int rr = i >> 6, kk = i & 63;
            int gr = base + rr;
            float v = (gr < n) ? X[gr * 64 + kk] : 0.0f;
            if (relu_in) v = fmaxf(v, 0.0f);
            xs[rr][kk] = v;
        }
        __syncthreads();
        float a0 = 0.f, a1 = 0.f, a2 = 0.f, a3 = 0.f;
        int r0 = rq * 4;
#pragma unroll
        for (int k = 0; k < 64; ++k) {
            float w = ws[k][c];
            a0 += xs[r0 + 0][k] * w;
            a1 += xs[r0 + 1][k] * w;
            a2 += xs[r0 + 2][k] * w;
            a3 += xs[r0 + 3][k] * w;
        }
        int gr = base + r0;
        if (gr + 0 < n) Y[(gr + 0) * 64 + c] = a0;
        if (gr + 1 < n) Y[(gr + 1) * 64 + c] = a1;
        if (gr + 2 < n) Y[(gr + 2) * 64 + c] = a2;
        if (gr + 3 < n) Y[(gr + 3) * 64 + c] = a3;
    }
}

// ---------------- CSR gather: out[c] = b + dinv2[c]*xw[c] + sum_e w_e * xw[src_e] ----------------
// One wave per destination node; lane = feature. 4-edge unroll for gather-latency ILP.

__global__ void k_gather(const float* __restrict__ xw, const float* __restrict__ dinv2,
                         const float* __restrict__ b, const int* __restrict__ rowptr,
                         const int2* __restrict__ edges, float* __restrict__ out, int n) {
    int lane = threadIdx.x & 63;
    int wv = blockIdx.x * (blockDim.x >> 6) + (threadIdx.x >> 6);
    int nw = gridDim.x * (blockDim.x >> 6);
    float bb = b[lane];
    for (int node = wv; node < n; node += nw) {
        float acc0 = bb + dinv2[node] * xw[node * 64 + lane];
        float acc1 = 0.f, acc2 = 0.f, acc3 = 0.f;
        int p  = (node == 0) ? 0 : rowptr[node - 1];  // post-fill convention
        int pe = rowptr[node];
        for (; p + 4 <= pe; p += 4) {
            int2 e0 = edges[p + 0];
            int2 e1 = edges[p + 1];
            int2 e2 = edges[p + 2];
            int2 e3 = edges[p + 3];
            acc0 += __int_as_float(e0.y) * xw[e0.x * 64 + lane];
            acc1 += __int_as_float(e1.y) * xw[e1.x * 64 + lane];
            acc2 += __int_as_float(e2.y) * xw[e2.x * 64 + lane];
            acc3 += __int_as_float(e3.y) * xw[e3.x * 64 + lane];
        }
        for (; p < pe; ++p) {
            int2 e = edges[p];
            acc0 += __int_as_float(e.y) * xw[e.x * 64 + lane];
        }
        out[node * 64 + lane] = (acc0 + acc1) + (acc2 + acc3);
    }
}

// ---------------- fused head: relu -> @Wm1+bm1 -> relu -> @Wm2+bm2 -> sigmoid ----------------

__global__ void k_final(const float* __restrict__ acc2,
                        const float* __restrict__ Wm1, const float* __restrict__ bm1,
                        const float* __restrict__ Wm2, const float* __restrict__ bm2,
                        float* __restrict__ out, int n) {
    __shared__ float w1[64][64];
    __shared__ float w2[64][16];
    __shared__ float sb1[64];
    __shared__ float sb2[16];
    __shared__ float h2s[4][64];
    __shared__ float h3s[4][64];
    int tid = threadIdx.x;
    for (int i = tid; i < 64 * 64; i += 256) w1[i >> 6][i & 63] = Wm1[i];
    for (int i = tid; i < 64 * 16; i += 256) w2[i >> 4][i & 15] = Wm2[i];
    if (tid < 64) sb1[tid] = bm1[tid];
    if (tid < 16) sb2[tid] = bm2[tid];

    int w = tid >> 6, lane = tid & 63;
    int ngrp = (n + 3) >> 2;
    for (int g = blockIdx.x; g < ngrp; g += gridDim.x) {
        int node = g * 4 + w;
        __syncthreads();
        if (node < n) h2s[w][lane] = fmaxf(acc2[node * 64 + lane], 0.0f);
        __syncthreads();
        float s = sb1[lane];
#pragma unroll
        for (int k = 0; k < 64; ++k) s += h2s[w][k] * w1[k][lane];
        h3s[w][lane] = fmaxf(s, 0.0f);
        __syncthreads();
        if (lane < 16 && node < n) {
            float s2 = sb2[lane];
#pragma unroll
            for (int k = 0; k < 64; ++k) s2 += h3s[w][k] * w2[k][lane];
            out[node * 16 + lane] = 1.0f / (1.0f + expf(-s2));
        }
    }
}

// ---------------- launch ----------------

extern "C" void kernel_launch(void* const* d_in, const int* in_sizes, int n_in,
                              void* d_out, int out_size, void* d_ws, size_t ws_size,
                              hipStream_t stream) {
    const float* x   = (const float*)d_in[0];
    const int*   ei  = (const int*)d_in[1];
    const float* ew  = (const float*)d_in[2];
    const float* W1  = (const float*)d_in[3];
    const float* b1  = (const float*)d_in[4];
    const float* W2  = (const float*)d_in[5];
    const float* b2  = (const float*)d_in[6];
    const float* Wm1 = (const float*)d_in[7];
    const float* bm1 = (const float*)d_in[8];
    const float* Wm2 = (const float*)d_in[9];
    const float* bm2 = (const float*)d_in[10];

    int n = in_sizes[0] / D;     // 50000
    int E = in_sizes[1] / 2;     // 800000
    const int* row = ei;
    const int* col = ei + E;

    // workspace layout (8B-aligned first)
    char* wsb = (char*)d_ws;
    int2*  edges  = (int2*)wsb;                     // E * 8 B
    float* xw     = (float*)(edges + E);            // n*64 f
    float* acc    = xw + (size_t)n * D;             // n*64 f
    float* deg    = acc + (size_t)n * D;            // n f (becomes dinv)
    float* dinv2  = deg + n;                        // n f
    int*   cnt    = (int*)(dinv2 + n);              // n i
    int*   rowptr = cnt + n;                        // n i
    float* out    = (float*)d_out;

    int gN = (n + 255) / 256;
    int gE = (E + 255) / 256;
    int ntiles = (n + 15) / 16;

    // CSR + norm build (shared by both conv layers)
    k_init<<<gN, 256, 0, stream>>>(deg, cnt, n);
    k_count<<<gE, 256, 0, stream>>>(col, ew, deg, cnt, E);
    k_dinv<<<gN, 256, 0, stream>>>(deg, dinv2, n);
    k_scan<<<1, 1024, 0, stream>>>(cnt, rowptr, n);
    k_csr_fill<<<gE, 256, 0, stream>>>(row, col, ew, deg, rowptr, edges, E);

    // conv layer 1
    k_matmul<<<ntiles, 256, 0, stream>>>(x, W1, xw, n, 0);
    k_gather<<<(n + 3) / 4, 256, 0, stream>>>(xw, dinv2, b1, rowptr, edges, acc, n);

    // conv layer 2 (relu fused into matmul input read)
    k_matmul<<<ntiles, 256, 0, stream>>>(acc, W2, xw, n, 1);
    k_gather<<<(n + 3) / 4, 256, 0, stream>>>(xw, dinv2, b2, rowptr, edges, acc, n);

    // fused MLP head + sigmoid
    k_final<<<2048, 256, 0, stream>>>(acc, Wm1, bm1, Wm2, bm2, out, n);
}

// Round 3
// 739.104 us; speedup vs baseline: 1.3131x; 1.0923x over previous
//
#include <hip/hip_runtime.h>
#include <math.h>

#define D 64

// ---------------- init: deg = 1.0 (self-loop), cnt = 0 ----------------

__global__ void k_init(float* deg, int* cnt, int n) {
    int i = blockIdx.x * 256 + threadIdx.x;
    if (i < n) { deg[i] = 1.0f; cnt[i] = 0; }
}

// ---------------- per-edge: weighted in-degree + integer in-degree ----------------

__global__ void k_count(const int* __restrict__ col, const float* __restrict__ ew,
                        float* deg, int* cnt, int E) {
    int e = blockIdx.x * 256 + threadIdx.x;
    if (e < E) {
        int c = col[e];
        atomicAdd(&deg[c], ew[e]);
        atomicAdd(&cnt[c], 1);
    }
}

// ---------------- fused: exclusive scan of cnt -> rowptr  +  dinv/dinv2 ----------------
// single block, 1024 threads; each thread owns a contiguous chunk.

__global__ void k_scan_dinv(const int* __restrict__ cnt, int* __restrict__ rowptr,
                            float* __restrict__ deg, float* __restrict__ dinv2, int n) {
    __shared__ int sums[1024];
    int t = threadIdx.x;
    int chunk = (n + 1023) >> 10;
    int beg = t * chunk;
    int end = beg + chunk; if (end > n) end = n;
    int s = 0;
    for (int i = beg; i < end; ++i) {
        s += cnt[i];
        float d = deg[i];          // >= 1 always (self-loop)
        deg[i]   = rsqrtf(d);      // becomes dinv
        dinv2[i] = 1.0f / d;       // self-loop norm
    }
    int v = s;
    sums[t] = v;
    __syncthreads();
    for (int off = 1; off < 1024; off <<= 1) {
        int u = (t >= off) ? sums[t - off] : 0;
        __syncthreads();
        v += u;
        sums[t] = v;
        __syncthreads();
    }
    int run = v - s;  // exclusive prefix of this chunk
    for (int i = beg; i < end; ++i) {
        rowptr[i] = run;
        run += cnt[i];
    }
    // post-fill convention: segment c = [rowptr[c-1], rowptr[c])
}

// ---------------- CSR fill: bucket edges by destination ----------------

__global__ void k_csr_fill(const int* __restrict__ row, const int* __restrict__ col,
                           const float* __restrict__ ew, const float* __restrict__ dinv,
                           int* rowptr, int2* __restrict__ edges, int E) {
    int e = blockIdx.x * 256 + threadIdx.x;
    if (e < E) {
        int r = row[e], c = col[e];
        float w = dinv[r] * ew[e] * dinv[c];
        int p = atomicAdd(&rowptr[c], 1);
        edges[p] = make_int2(r, __float_as_int(w));
    }
}

// ---------------- dense matmul: Y = X @ W (layer 1 only) ----------------
// grid 1024 w/ tile loop so W is fetched once per block (16 MB total, not 50).

__global__ void k_mm1(const float* __restrict__ X, const float* __restrict__ W,
                      float* __restrict__ Y, int n) {
    __shared__ float ws[64][64];
    __shared__ float xs[16][64];
    int tid = threadIdx.x;
    int c  = tid & 63;
    int rq = tid >> 6;

    for (int i = tid; i < 64 * 64; i += 256) ws[i >> 6][i & 63] = W[i];

    int ntiles = (n + 15) >> 4;
    for (int t = blockIdx.x; t < ntiles; t += gridDim.x) {
        __syncthreads();
        int base = t * 16;
        for (int i = tid; i < 16 * 64; i += 256) {
            int rr = i >> 6, kk = i & 63;
            int gr = base + rr;
            xs[rr][kk] = (gr < n) ? X[gr * 64 + kk] : 0.0f;
        }
        __syncthreads();
        float a0 = 0.f, a1 = 0.f, a2 = 0.f, a3 = 0.f;
        int r0 = rq * 4;
#pragma unroll
        for (int k = 0; k < 64; ++k) {
            float w = ws[k][c];
            a0 += xs[r0 + 0][k] * w;
            a1 += xs[r0 + 1][k] * w;
            a2 += xs[r0 + 2][k] * w;
            a3 += xs[r0 + 3][k] * w;
        }
        int gr = base + r0;
        if (gr + 0 < n) Y[(gr + 0) * 64 + c] = a0;
        if (gr + 1 < n) Y[(gr + 1) * 64 + c] = a1;
        if (gr + 2 < n) Y[(gr + 2) * 64 + c] = a2;
        if (gr + 3 < n) Y[(gr + 3) * 64 + c] = a3;
    }
}

// ---------------- fused conv1-aggregate + relu + @W2 ----------------
// One wave per node (lane = feature). Gather in registers, then the 64x64
// matmul via per-wave LDS row (wave-synchronous, no block barriers in loop).

__global__ void k_gather_mm(const float* __restrict__ xw, const float* __restrict__ dinv2,
                            const float* __restrict__ b, const int* __restrict__ rowptr,
                            const int2* __restrict__ edges, const float* __restrict__ W,
                            float* __restrict__ out, int n) {
    __shared__ float ws[64][64];
    __shared__ float hs[4][64];
    int tid = threadIdx.x;
    for (int i = tid; i < 64 * 64; i += 256) ws[i >> 6][i & 63] = W[i];
    __syncthreads();

    int lane = tid & 63, w = tid >> 6;
    int wv = blockIdx.x * 4 + w;
    int nw = gridDim.x * 4;
    float bb = b[lane];
    for (int node = wv; node < n; node += nw) {
        float acc0 = bb + dinv2[node] * xw[node * 64 + lane];
        float acc1 = 0.f, acc2 = 0.f, acc3 = 0.f;
        int p  = (node == 0) ? 0 : rowptr[node - 1];
        int pe = rowptr[node];
        for (; p + 4 <= pe; p += 4) {
            int2 e0 = edges[p + 0];
            int2 e1 = edges[p + 1];
            int2 e2 = edges[p + 2];
            int2 e3 = edges[p + 3];
            acc0 += __int_as_float(e0.y) * xw[e0.x * 64 + lane];
            acc1 += __int_as_float(e1.y) * xw[e1.x * 64 + lane];
            acc2 += __int_as_float(e2.y) * xw[e2.x * 64 + lane];
            acc3 += __int_as_float(e3.y) * xw[e3.x * 64 + lane];
        }
        for (; p < pe; ++p) {
            int2 e = edges[p];
            acc0 += __int_as_float(e.y) * xw[e.x * 64 + lane];
        }
        // h1 = relu(aggregate); xw2 = h1 @ W2 (per-wave LDS broadcast)
        hs[w][lane] = fmaxf((acc0 + acc1) + (acc2 + acc3), 0.0f);
        float s = 0.f;
#pragma unroll
        for (int k = 0; k < 64; ++k) s += hs[w][k] * ws[k][lane];
        out[node * 64 + lane] = s;
    }
}

// ---------------- fused conv2-aggregate + relu + MLP head + sigmoid ----------------

__global__ void k_gather_head(const float* __restrict__ xw, const float* __restrict__ dinv2,
                              const float* __restrict__ b, const int* __restrict__ rowptr,
                              const int2* __restrict__ edges,
                              const float* __restrict__ Wm1, const float* __restrict__ bm1,
                              const float* __restrict__ Wm2, const float* __restrict__ bm2,
                              float* __restrict__ out, int n) {
    __shared__ float w1[64][64];
    __shared__ float w2[64][16];
    __shared__ float sb1[64];
    __shared__ float sb2[16];
    __shared__ float h2s[4][64];
    __shared__ float h3s[4][64];
    int tid = threadIdx.x;
    for (int i = tid; i < 64 * 64; i += 256) w1[i >> 6][i & 63] = Wm1[i];
    for (int i = tid; i < 64 * 16; i += 256) w2[i >> 4][i & 15] = Wm2[i];
    if (tid < 64) sb1[tid] = bm1[tid];
    if (tid < 16) sb2[tid] = bm2[tid];
    __syncthreads();

    int lane = tid & 63, w = tid >> 6;
    int wv = blockIdx.x * 4 + w;
    int nw = gridDim.x * 4;
    float bb = b[lane];
    for (int node = wv; node < n; node += nw) {
        float acc0 = bb + dinv2[node] * xw[node * 64 + lane];
        float acc1 = 0.f, acc2 = 0.f, acc3 = 0.f;
        int p  = (node == 0) ? 0 : rowptr[node - 1];
        int pe = rowptr[node];
        for (; p + 4 <= pe; p += 4) {
            int2 e0 = edges[p + 0];
            int2 e1 = edges[p + 1];
            int2 e2 = edges[p + 2];
            int2 e3 = edges[p + 3];
            acc0 += __int_as_float(e0.y) * xw[e0.x * 64 + lane];
            acc1 += __int_as_float(e1.y) * xw[e1.x * 64 + lane];
            acc2 += __int_as_float(e2.y) * xw[e2.x * 64 + lane];
            acc3 += __int_as_float(e3.y) * xw[e3.x * 64 + lane];
        }
        for (; p < pe; ++p) {
            int2 e = edges[p];
            acc0 += __int_as_float(e.y) * xw[e.x * 64 + lane];
        }
        // h2 = relu(aggregate)
        h2s[w][lane] = fmaxf((acc0 + acc1) + (acc2 + acc3), 0.0f);
        // h3 = relu(h2 @ Wm1 + bm1)   (per-wave, wave-synchronous LDS)
        float s = sb1[lane];
#pragma unroll
        for (int k = 0; k < 64; ++k) s += h2s[w][k] * w1[k][lane];
        h3s[w][lane] = fmaxf(s, 0.0f);
        // logits = h3 @ Wm2 + bm2 ; out = sigmoid
        if (lane < 16) {
            float s2 = sb2[lane];
#pragma unroll
            for (int k = 0; k < 64; ++k) s2 += h3s[w][k] * w2[k][lane];
            out[node * 16 + lane] = 1.0f / (1.0f + expf(-s2));
        }
    }
}

// ---------------- launch ----------------

extern "C" void kernel_launch(void* const* d_in, const int* in_sizes, int n_in,
                              void* d_out, int out_size, void* d_ws, size_t ws_size,
                              hipStream_t stream) {
    const float* x   = (const float*)d_in[0];
    const int*   ei  = (const int*)d_in[1];
    const float* ew  = (const float*)d_in[2];
    const float* W1  = (const float*)d_in[3];
    const float* b1  = (const float*)d_in[4];
    const float* W2  = (const float*)d_in[5];
    const float* b2  = (const float*)d_in[6];
    const float* Wm1 = (const float*)d_in[7];
    const float* bm1 = (const float*)d_in[8];
    const float* Wm2 = (const float*)d_in[9];
    const float* bm2 = (const float*)d_in[10];

    int n = in_sizes[0] / D;     // 50000
    int E = in_sizes[1] / 2;     // 800000
    const int* row = ei;
    const int* col = ei + E;

    // workspace layout (8B-aligned first)
    char* wsb = (char*)d_ws;
    int2*  edges  = (int2*)wsb;                     // E * 8 B
    float* xw1    = (float*)(edges + E);            // n*64 f
    float* xw2    = xw1 + (size_t)n * D;            // n*64 f
    float* deg    = xw2 + (size_t)n * D;            // n f (becomes dinv)
    float* dinv2  = deg + n;                        // n f
    int*   cnt    = (int*)(dinv2 + n);              // n i
    int*   rowptr = cnt + n;                        // n i
    float* out    = (float*)d_out;

    int gN = (n + 255) / 256;
    int gE = (E + 255) / 256;

    // CSR + norm build (shared by both conv layers)
    k_init<<<gN, 256, 0, stream>>>(deg, cnt, n);
    k_count<<<gE, 256, 0, stream>>>(col, ew, deg, cnt, E);
    k_scan_dinv<<<1, 1024, 0, stream>>>(cnt, rowptr, deg, dinv2, n);
    k_csr_fill<<<gE, 256, 0, stream>>>(row, col, ew, deg, rowptr, edges, E);

    // layer 1 dense: xw1 = x @ W1
    k_mm1<<<1024, 256, 0, stream>>>(x, W1, xw1, n);

    // fused: conv1 aggregate + relu + @W2  -> xw2
    k_gather_mm<<<2048, 256, 0, stream>>>(xw1, dinv2, b1, rowptr, edges, W2, xw2, n);

    // fused: conv2 aggregate + relu + MLP head + sigmoid -> out
    k_gather_head<<<2048, 256, 0, stream>>>(xw2, dinv2, b2, rowptr, edges,
                                            Wm1, bm1, Wm2, bm2, out, n);
}

// Round 5
// 523.364 us; speedup vs baseline: 1.8544x; 1.4122x over previous
//
#include <hip/hip_runtime.h>
#include <math.h>

#define D 64

// ---------------- init: deg = 1.0 (self-loop), cnt = 0 ----------------

__global__ void k_init(float* deg, int* cnt, int n) {
    int i = blockIdx.x * 256 + threadIdx.x;
    if (i < n) { deg[i] = 1.0f; cnt[i] = 0; }
}

// ---------------- per-edge: weighted in-degree + integer in-degree ----------------

__global__ void k_count(const int* __restrict__ col, const float* __restrict__ ew,
                        float* deg, int* cnt, int E) {
    int e = blockIdx.x * 256 + threadIdx.x;
    if (e < E) {
        int c = col[e];
        atomicAdd(&deg[c], ew[e]);
        atomicAdd(&cnt[c], 1);
    }
}

// ---------------- dinv = rsqrt(deg), dinv2 = 1/deg (full-grid, coalesced) ----------------

__global__ void k_dinv(float* deg, float* dinv2, int n) {
    int i = blockIdx.x * 256 + threadIdx.x;
    if (i < n) {
        float d = deg[i];            // >= 1 always (self-loop)
        deg[i]   = rsqrtf(d);        // becomes dinv
        dinv2[i] = 1.0f / d;
    }
}

// ---------------- exclusive scan of cnt -> rowptr ----------------
// Single block, 1024 threads, coalesced: tiles of 4096 (int4/lane),
// wave-level shfl scan + cross-wave LDS offsets (2 barriers/tile).

__global__ void k_scan(const int* __restrict__ cnt, int* __restrict__ rowptr, int n) {
    __shared__ int wsum[16];
    int t = threadIdx.x;
    int lane = t & 63, wave = t >> 6;
    int base = 0;
    int ntiles = (n + 4095) >> 12;
    for (int tile = 0; tile < ntiles; ++tile) {
        int i0 = (tile << 12) + t * 4;
        int c0 = 0, c1 = 0, c2 = 0, c3 = 0;
        if (i0 + 3 < n) {
            const int4 c4 = *(const int4*)(cnt + i0);
            c0 = c4.x; c1 = c4.y; c2 = c4.z; c3 = c4.w;
        } else {
            if (i0 + 0 < n) c0 = cnt[i0 + 0];
            if (i0 + 1 < n) c1 = cnt[i0 + 1];
            if (i0 + 2 < n) c2 = cnt[i0 + 2];
        }
        int s = c0 + c1 + c2 + c3;
        int incl = s;
#pragma unroll
        for (int off = 1; off < 64; off <<= 1) {
            int u = __shfl_up(incl, off, 64);
            if (lane >= off) incl += u;
        }
        if (lane == 63) wsum[wave] = incl;
        __syncthreads();
        int wpre = 0, tot = 0;
#pragma unroll
        for (int w = 0; w < 16; ++w) {
            int v = wsum[w];
            if (w < wave) wpre += v;
            tot += v;
        }
        int ex = base + wpre + (incl - s);  // exclusive prefix of element i0
        if (i0 + 3 < n) {
            int4 r;
            r.x = ex;
            r.y = ex + c0;
            r.z = ex + c0 + c1;
            r.w = ex + c0 + c1 + c2;
            *(int4*)(rowptr + i0) = r;
        } else {
            if (i0 + 0 < n) rowptr[i0 + 0] = ex;
            if (i0 + 1 < n) rowptr[i0 + 1] = ex + c0;
            if (i0 + 2 < n) rowptr[i0 + 2] = ex + c0 + c1;
        }
        base += tot;
        __syncthreads();  // wsum reused next tile
    }
    // post-fill convention: segment c = [rowptr[c-1], rowptr[c])
}

// ---------------- CSR fill: bucket edges by destination ----------------

__global__ void k_csr_fill(const int* __restrict__ row, const int* __restrict__ col,
                           const float* __restrict__ ew, const float* __restrict__ dinv,
                           int* rowptr, int2* __restrict__ edges, int E) {
    int e = blockIdx.x * 256 + threadIdx.x;
    if (e < E) {
        int r = row[e], c = col[e];
        float w = dinv[r] * ew[e] * dinv[c];
        int p = atomicAdd(&rowptr[c], 1);
        edges[p] = make_int2(r, __float_as_int(w));
    }
}

// ---------------- dense matmul: Y = X @ W (layer 1 only) ----------------

__global__ void k_mm1(const float* __restrict__ X, const float* __restrict__ W,
                      float* __restrict__ Y, int n) {
    __shared__ float ws[64][64];
    __shared__ float xs[16][64];
    int tid = threadIdx.x;
    int c  = tid & 63;
    int rq = tid >> 6;

    for (int i = tid; i < 64 * 64; i += 256) ws[i >> 6][i & 63] = W[i];

    int ntiles = (n + 15) >> 4;
    for (int t = blockIdx.x; t < ntiles; t += gridDim.x) {
        __syncthreads();
        int base = t * 16;
        for (int i = tid; i < 16 * 64; i += 256) {
            int rr = i >> 6, kk = i & 63;
            int gr = base + rr;
            xs[rr][kk] = (gr < n) ? X[gr * 64 + kk] : 0.0f;
        }
        __syncthreads();
        float a0 = 0.f, a1 = 0.f, a2 = 0.f, a3 = 0.f;
        int r0 = rq * 4;
#pragma unroll
        for (int k = 0; k < 64; ++k) {
            float w = ws[k][c];
            a0 += xs[r0 + 0][k] * w;
            a1 += xs[r0 + 1][k] * w;
            a2 += xs[r0 + 2][k] * w;
            a3 += xs[r0 + 3][k] * w;
        }
        int gr = base + r0;
        if (gr + 0 < n) Y[(gr + 0) * 64 + c] = a0;
        if (gr + 1 < n) Y[(gr + 1) * 64 + c] = a1;
        if (gr + 2 < n) Y[(gr + 2) * 64 + c] = a2;
        if (gr + 3 < n) Y[(gr + 3) * 64 + c] = a3;
    }
}

// ---------------- fused conv1-aggregate + relu + @W2 ----------------
// Block-uniform group loop + explicit barriers between LDS write/read phases
// (wave-synchronous LDS without barriers raced — round 4 post-mortem).

__global__ void k_gather_mm(const float* __restrict__ xw, const float* __restrict__ dinv2,
                            const float* __restrict__ b, const int* __restrict__ rowptr,
                            const int2* __restrict__ edges, const float* __restrict__ W,
                            float* __restrict__ out, int n) {
    __shared__ float ws[64][64];
    __shared__ float hs[4][64];
    int tid = threadIdx.x;
    for (int i = tid; i < 64 * 64; i += 256) ws[i >> 6][i & 63] = W[i];

    int lane = tid & 63, w = tid >> 6;
    int ngrp = (n + 3) >> 2;
    for (int g = blockIdx.x; g < ngrp; g += gridDim.x) {
        int node = g * 4 + w;
        __syncthreads();  // ws ready (1st iter) / hs free (later iters)
        if (node < n) {
            float acc0 = b[lane] + dinv2[node] * xw[node * 64 + lane];
            float acc1 = 0.f, acc2 = 0.f, acc3 = 0.f;
            int p  = (node == 0) ? 0 : rowptr[node - 1];
            int pe = rowptr[node];
            for (; p + 4 <= pe; p += 4) {
                int2 e0 = edges[p + 0];
                int2 e1 = edges[p + 1];
                int2 e2 = edges[p + 2];
                int2 e3 = edges[p + 3];
                acc0 += __int_as_float(e0.y) * xw[e0.x * 64 + lane];
                acc1 += __int_as_float(e1.y) * xw[e1.x * 64 + lane];
                acc2 += __int_as_float(e2.y) * xw[e2.x * 64 + lane];
                acc3 += __int_as_float(e3.y) * xw[e3.x * 64 + lane];
            }
            for (; p < pe; ++p) {
                int2 e = edges[p];
                acc0 += __int_as_float(e.y) * xw[e.x * 64 + lane];
            }
            hs[w][lane] = fmaxf((acc0 + acc1) + (acc2 + acc3), 0.0f);
        }
        __syncthreads();  // hs ready
        if (node < n) {
            float s = 0.f;
#pragma unroll
            for (int k = 0; k < 64; ++k) s += hs[w][k] * ws[k][lane];
            out[node * 64 + lane] = s;
        }
    }
}

// ---------------- fused conv2-aggregate + relu + MLP head + sigmoid ----------------

__global__ void k_gather_head(const float* __restrict__ xw, const float* __restrict__ dinv2,
                              const float* __restrict__ b, const int* __restrict__ rowptr,
                              const int2* __restrict__ edges,
                              const float* __restrict__ Wm1, const float* __restrict__ bm1,
                              const float* __restrict__ Wm2, const float* __restrict__ bm2,
                              float* __restrict__ out, int n) {
    __shared__ float w1[64][64];
    __shared__ float w2[64][16];
    __shared__ float sb1[64];
    __shared__ float sb2[16];
    __shared__ float h2s[4][64];
    __shared__ float h3s[4][64];
    int tid = threadIdx.x;
    for (int i = tid; i < 64 * 64; i += 256) w1[i >> 6][i & 63] = Wm1[i];
    for (int i = tid; i < 64 * 16; i += 256) w2[i >> 4][i & 15] = Wm2[i];
    if (tid < 64) sb1[tid] = bm1[tid];
    if (tid < 16) sb2[tid] = bm2[tid];

    int lane = tid & 63, w = tid >> 6;
    int ngrp = (n + 3) >> 2;
    for (int g = blockIdx.x; g < ngrp; g += gridDim.x) {
        int node = g * 4 + w;
        __syncthreads();  // weights ready (1st iter) / h2s,h3s free (later iters)
        if (node < n) {
            float acc0 = b[lane] + dinv2[node] * xw[node * 64 + lane];
            float acc1 = 0.f, acc2 = 0.f, acc3 = 0.f;
            int p  = (node == 0) ? 0 : rowptr[node - 1];
            int pe = rowptr[node];
            for (; p + 4 <= pe; p += 4) {
                int2 e0 = edges[p + 0];
                int2 e1 = edges[p + 1];
                int2 e2 = edges[p + 2];
                int2 e3 = edges[p + 3];
                acc0 += __int_as_float(e0.y) * xw[e0.x * 64 + lane];
                acc1 += __int_as_float(e1.y) * xw[e1.x * 64 + lane];
                acc2 += __int_as_float(e2.y) * xw[e2.x * 64 + lane];
                acc3 += __int_as_float(e3.y) * xw[e3.x * 64 + lane];
            }
            for (; p < pe; ++p) {
                int2 e = edges[p];
                acc0 += __int_as_float(e.y) * xw[e.x * 64 + lane];
            }
            h2s[w][lane] = fmaxf((acc0 + acc1) + (acc2 + acc3), 0.0f);
        }
        __syncthreads();  // h2s ready
        if (node < n) {
            float s = sb1[lane];
#pragma unroll
            for (int k = 0; k < 64; ++k) s += h2s[w][k] * w1[k][lane];
            h3s[w][lane] = fmaxf(s, 0.0f);
        }
        __syncthreads();  // h3s ready
        if (node < n && lane < 16) {
            float s2 = sb2[lane];
#pragma unroll
            for (int k = 0; k < 64; ++k) s2 += h3s[w][k] * w2[k][lane];
            out[node * 16 + lane] = 1.0f / (1.0f + expf(-s2));
        }
    }
}

// ---------------- launch ----------------

extern "C" void kernel_launch(void* const* d_in, const int* in_sizes, int n_in,
                              void* d_out, int out_size, void* d_ws, size_t ws_size,
                              hipStream_t stream) {
    const float* x   = (const float*)d_in[0];
    const int*   ei  = (const int*)d_in[1];
    const float* ew  = (const float*)d_in[2];
    const float* W1  = (const float*)d_in[3];
    const float* b1  = (const float*)d_in[4];
    const float* W2  = (const float*)d_in[5];
    const float* b2  = (const float*)d_in[6];
    const float* Wm1 = (const float*)d_in[7];
    const float* bm1 = (const float*)d_in[8];
    const float* Wm2 = (const float*)d_in[9];
    const float* bm2 = (const float*)d_in[10];

    int n = in_sizes[0] / D;     // 50000
    int E = in_sizes[1] / 2;     // 800000
    const int* row = ei;
    const int* col = ei + E;

    // workspace layout (16B-aligned: all block sizes divisible by 16 B)
    char* wsb = (char*)d_ws;
    int2*  edges  = (int2*)wsb;                     // E * 8 B
    float* xw1    = (float*)(edges + E);            // n*64 f
    float* xw2    = xw1 + (size_t)n * D;            // n*64 f
    float* deg    = xw2 + (size_t)n * D;            // n f (becomes dinv)
    float* dinv2  = deg + n;                        // n f
    int*   cnt    = (int*)(dinv2 + n);              // n i
    int*   rowptr = cnt + n;                        // n i
    float* out    = (float*)d_out;

    int gN = (n + 255) / 256;
    int gE = (E + 255) / 256;

    // CSR + norm build (shared by both conv layers)
    k_init<<<gN, 256, 0, stream>>>(deg, cnt, n);
    k_count<<<gE, 256, 0, stream>>>(col, ew, deg, cnt, E);
    k_dinv<<<gN, 256, 0, stream>>>(deg, dinv2, n);
    k_scan<<<1, 1024, 0, stream>>>(cnt, rowptr, n);
    k_csr_fill<<<gE, 256, 0, stream>>>(row, col, ew, deg, rowptr, edges, E);

    // layer 1 dense: xw1 = x @ W1
    k_mm1<<<1024, 256, 0, stream>>>(x, W1, xw1, n);

    // fused: conv1 aggregate + relu + @W2  -> xw2
    k_gather_mm<<<2048, 256, 0, stream>>>(xw1, dinv2, b1, rowptr, edges, W2, xw2, n);

    // fused: conv2 aggregate + relu + MLP head + sigmoid -> out
    k_gather_head<<<2048, 256, 0, stream>>>(xw2, dinv2, b2, rowptr, edges,
                                            Wm1, bm1, Wm2, bm2, out, n);
}

// Round 7
// 397.521 us; speedup vs baseline: 2.4415x; 1.3166x over previous
//
#include <hip/hip_runtime.h>
#include <math.h>

#define D 64

// LDS pool for the dense-matmul branch (20 KB).
struct SmemMM {
    float A[64 * 64];   // W
    float B[16 * 64];   // x tile
};

// ---------------- K1: zero the packed count/degree array ----------------

__global__ void k_zero(unsigned long long* packed, int n) {
    int i = blockIdx.x * 256 + threadIdx.x;
    if (i < n) packed[i] = 0ull;
}

// ---------------- K2: edge count (one u64 atomic) + mm1, block-range split ----------------
// packed[c] += (1<<48) | round(ew * 2^32).  Per-node: count < 2^16, wsum < 2^38 -> carry-free.

__global__ void __launch_bounds__(256) k_count_mm1(
        const int* __restrict__ col, const float* __restrict__ ew,
        unsigned long long* __restrict__ packed, int E, int cntBlocks,
        const float* __restrict__ X, const float* __restrict__ W1,
        float* __restrict__ Y, int n) {
    __shared__ SmemMM sm;
    if (blockIdx.x < cntBlocks) {
        int e = blockIdx.x * 256 + threadIdx.x;
        if (e < E) {
            unsigned long long add = (1ull << 48) |
                (unsigned long long)(ew[e] * 4294967296.0f + 0.5f);
            atomicAdd(&packed[col[e]], add);
        }
    } else {
        // dense matmul: Y = X @ W1
        int bid = blockIdx.x - cntBlocks;
        int nblk = gridDim.x - cntBlocks;
        int tid = threadIdx.x;
        int c = tid & 63, rq = tid >> 6;
        for (int i = tid; i < 4096; i += 256) sm.A[i] = W1[i];
        int ntile = (n + 15) >> 4;
        for (int t = bid; t < ntile; t += nblk) {
            __syncthreads();  // A ready (1st) / B free (later)
            int base = t * 16;
            for (int i = tid; i < 1024; i += 256) {
                int rr = i >> 6, kk = i & 63;
                int gr = base + rr;
                sm.B[i] = (gr < n) ? X[gr * 64 + kk] : 0.0f;
            }
            __syncthreads();
            float a0 = 0.f, a1 = 0.f, a2 = 0.f, a3 = 0.f;
            int r0 = rq * 4;
#pragma unroll
            for (int k = 0; k < 64; ++k) {
                float w = sm.A[k * 64 + c];
                a0 += sm.B[(r0 + 0) * 64 + k] * w;
                a1 += sm.B[(r0 + 1) * 64 + k] * w;
                a2 += sm.B[(r0 + 2) * 64 + k] * w;
                a3 += sm.B[(r0 + 3) * 64 + k] * w;
            }
            int gr = base + r0;
            if (gr + 0 < n) Y[(gr + 0) * 64 + c] = a0;
            if (gr + 1 < n) Y[(gr + 1) * 64 + c] = a1;
            if (gr + 2 < n) Y[(gr + 2) * 64 + c] = a2;
            if (gr + 3 < n) Y[(gr + 3) * 64 + c] = a3;
        }
    }
}

// ---------------- K3: dinv (all blocks) + exclusive scan -> rowptr (block 0) ----------------

__global__ void k_dinv_scan(const unsigned long long* __restrict__ packed,
                            float* __restrict__ dinv, int* __restrict__ rowptr, int n) {
    int i = blockIdx.x * 256 + threadIdx.x;
    if (i < n) {
        unsigned long long v = packed[i];
        float deg = 1.0f + (float)((double)(v & 0x0000FFFFFFFFFFFFull) * (1.0 / 4294967296.0));
        dinv[i] = rsqrtf(deg);   // deg >= 1 (self-loop); quantization ~1e-8
    }
    if (blockIdx.x == 0) {
        // coalesced single-block scan of hi-16 counts; 256 thr, tiles of 1024
        __shared__ int wscr[4];
        int t = threadIdx.x, lane = t & 63, wave = t >> 6;
        int base = 0;
        int ntiles = (n + 1023) >> 10;
        for (int tile = 0; tile < ntiles; ++tile) {
            int i0 = (tile << 10) + t * 4;
            int c0 = (i0 + 0 < n) ? (int)(packed[i0 + 0] >> 48) : 0;
            int c1 = (i0 + 1 < n) ? (int)(packed[i0 + 1] >> 48) : 0;
            int c2 = (i0 + 2 < n) ? (int)(packed[i0 + 2] >> 48) : 0;
            int c3 = (i0 + 3 < n) ? (int)(packed[i0 + 3] >> 48) : 0;
            int s = c0 + c1 + c2 + c3, incl = s;
#pragma unroll
            for (int off = 1; off < 64; off <<= 1) {
                int u = __shfl_up(incl, off, 64);
                if (lane >= off) incl += u;
            }
            if (lane == 63) wscr[wave] = incl;
            __syncthreads();
            int wpre = 0, tot = 0;
#pragma unroll
            for (int w = 0; w < 4; ++w) { int v = wscr[w]; if (w < wave) wpre += v; tot += v; }
            int ex = base + wpre + (incl - s);
            if (i0 + 0 < n) rowptr[i0 + 0] = ex;
            if (i0 + 1 < n) rowptr[i0 + 1] = ex + c0;
            if (i0 + 2 < n) rowptr[i0 + 2] = ex + c0 + c1;
            if (i0 + 3 < n) rowptr[i0 + 3] = ex + c0 + c1 + c2;
            base += tot;
            __syncthreads();
        }
        // post-fill convention: segment c = [rowptr[c-1], rowptr[c])
    }
}

// ---------------- K4: CSR fill (weight = dinv[row]*ew; dinv[col] folded at gather) ----------------

__global__ void k_fill(const int* __restrict__ row, const int* __restrict__ col,
                       const float* __restrict__ ew, const float* __restrict__ dinv,
                       int* rowptr, int2* __restrict__ edges, int E) {
    int e = blockIdx.x * 256 + threadIdx.x;
    if (e < E) {
        int r = row[e];
        float wv = dinv[r] * ew[e];
        int p = atomicAdd(&rowptr[col[e]], 1);
        edges[p] = make_int2(r, __float_as_int(wv));
    }
}

// ---------------- per-node aggregate (wave-wide, lane = feature) ----------------
// returns dinv[c] * ( dinv[c]*xw[c] + sum_e (dinv[r]*ew)*xw[r] ) + b

__device__ __forceinline__ float gather_node(const float* __restrict__ xw,
                                             const int* __restrict__ rowptr,
                                             const int2* __restrict__ edges,
                                             float d, float bb, int node, int lane) {
    float acc0 = d * xw[node * 64 + lane];   // self-loop
    float acc1 = 0.f, acc2 = 0.f, acc3 = 0.f;
    int p  = (node == 0) ? 0 : rowptr[node - 1];
    int pe = rowptr[node];
    for (; p + 4 <= pe; p += 4) {
        int2 e0 = edges[p + 0];
        int2 e1 = edges[p + 1];
        int2 e2 = edges[p + 2];
        int2 e3 = edges[p + 3];
        acc0 += __int_as_float(e0.y) * xw[e0.x * 64 + lane];
        acc1 += __int_as_float(e1.y) * xw[e1.x * 64 + lane];
        acc2 += __int_as_float(e2.y) * xw[e2.x * 64 + lane];
        acc3 += __int_as_float(e3.y) * xw[e3.x * 64 + lane];
    }
    for (; p < pe; ++p) {
        int2 e = edges[p];
        acc0 += __int_as_float(e.y) * xw[e.x * 64 + lane];
    }
    return d * ((acc0 + acc1) + (acc2 + acc3)) + bb;
}

// ---------------- K5: conv1 aggregate + relu + @W2 ----------------
// Block-uniform group loop + barriers between LDS phases (round-4 race lesson).

__global__ void k_gather_mm(const float* __restrict__ xw, const float* __restrict__ dinv,
                            const float* __restrict__ b, const int* __restrict__ rowptr,
                            const int2* __restrict__ edges, const float* __restrict__ W,
                            float* __restrict__ out, int n) {
    __shared__ float ws[64][64];
    __shared__ float hs[4][64];
    int tid = threadIdx.x;
    for (int i = tid; i < 4096; i += 256) ws[i >> 6][i & 63] = W[i];

    int lane = tid & 63, w = tid >> 6;
    float bb = b[lane];
    int ngrp = (n + 3) >> 2;
    for (int g = blockIdx.x; g < ngrp; g += gridDim.x) {
        int node = g * 4 + w;
        __syncthreads();  // ws ready (1st) / hs free (later)
        if (node < n)
            hs[w][lane] = fmaxf(gather_node(xw, rowptr, edges, dinv[node], bb, node, lane), 0.0f);
        __syncthreads();  // hs ready
        if (node < n) {
            float s = 0.f;
#pragma unroll
            for (int k = 0; k < 64; ++k) s += hs[w][k] * ws[k][lane];
            out[node * 64 + lane] = s;
        }
    }
}

// ---------------- K6: conv2 aggregate + relu + MLP head + sigmoid ----------------

__global__ void k_gather_head(const float* __restrict__ xw, const float* __restrict__ dinv,
                              const float* __restrict__ b, const int* __restrict__ rowptr,
                              const int2* __restrict__ edges,
                              const float* __restrict__ Wm1, const float* __restrict__ bm1,
                              const float* __restrict__ Wm2, const float* __restrict__ bm2,
                              float* __restrict__ out, int n) {
    __shared__ float w1[64][64];
    __shared__ float w2[64][16];
    __shared__ float sb1[64];
    __shared__ float sb2[16];
    __shared__ float h2s[4][64];
    __shared__ float h3s[4][64];
    int tid = threadIdx.x;
    for (int i = tid; i < 4096; i += 256) w1[i >> 6][i & 63] = Wm1[i];
    for (int i = tid; i < 1024; i += 256) w2[i >> 4][i & 15] = Wm2[i];
    if (tid < 64) sb1[tid] = bm1[tid];
    if (tid < 16) sb2[tid] = bm2[tid];

    int lane = tid & 63, w = tid >> 6;
    float bb = b[lane];
    int ngrp = (n + 3) >> 2;
    for (int g = blockIdx.x; g < ngrp; g += gridDim.x) {
        int node = g * 4 + w;
        __syncthreads();  // weights ready (1st) / h2s,h3s free (later)
        if (node < n)
            h2s[w][lane] = fmaxf(gather_node(xw, rowptr, edges, dinv[node], bb, node, lane), 0.0f);
        __syncthreads();  // h2s ready
        if (node < n) {
            float s = sb1[lane];
#pragma unroll
            for (int k = 0; k < 64; ++k) s += h2s[w][k] * w1[k][lane];
            h3s[w][lane] = fmaxf(s, 0.0f);
        }
        __syncthreads();  // h3s ready
        if (node < n && lane < 16) {
            float s2 = sb2[lane];
#pragma unroll
            for (int k = 0; k < 64; ++k) s2 += h3s[w][k] * w2[k][lane];
            out[node * 16 + lane] = 1.0f / (1.0f + expf(-s2));
        }
    }
}

// ---------------- launch ----------------

extern "C" void kernel_launch(void* const* d_in, const int* in_sizes, int n_in,
                              void* d_out, int out_size, void* d_ws, size_t ws_size,
                              hipStream_t stream) {
    const float* x   = (const float*)d_in[0];
    const int*   ei  = (const int*)d_in[1];
    const float* ew  = (const float*)d_in[2];
    const float* W1  = (const float*)d_in[3];
    const float* b1  = (const float*)d_in[4];
    const float* W2  = (const float*)d_in[5];
    const float* b2  = (const float*)d_in[6];
    const float* Wm1 = (const float*)d_in[7];
    const float* bm1 = (const float*)d_in[8];
    const float* Wm2 = (const float*)d_in[9];
    const float* bm2 = (const float*)d_in[10];

    int n = in_sizes[0] / D;     // 50000
    int E = in_sizes[1] / 2;     // 800000
    const int* row = ei;
    const int* col = ei + E;

    // workspace layout (all segment sizes multiples of 16 B)
    char* wsb = (char*)d_ws;
    unsigned long long* packed = (unsigned long long*)wsb;   // n * 8 B
    int2*  edges  = (int2*)(packed + n);                     // E * 8 B
    float* xw1    = (float*)(edges + E);                     // n*64 f
    float* xw2    = xw1 + (size_t)n * D;                     // n*64 f
    float* dinv   = xw2 + (size_t)n * D;                     // n f
    int*   rowptr = (int*)(dinv + n);                        // n i
    float* outp   = (float*)d_out;

    int gN = (n + 255) / 256;
    int gE = (E + 255) / 256;
    int mmBlocks = 1024;

    // K1: zero packed
    k_zero<<<gN, 256, 0, stream>>>(packed, n);
    // K2: edge count (u64 packed) + mm1 (xw1 = x @ W1), block-range split
    k_count_mm1<<<gE + mmBlocks, 256, 0, stream>>>(col, ew, packed, E, gE, x, W1, xw1, n);
    // K3: dinv + single-block scan -> rowptr
    k_dinv_scan<<<gN, 256, 0, stream>>>(packed, dinv, rowptr, n);
    // K4: CSR fill
    k_fill<<<gE, 256, 0, stream>>>(row, col, ew, dinv, rowptr, edges, E);
    // K5: conv1 aggregate + relu + @W2 -> xw2
    k_gather_mm<<<2048, 256, 0, stream>>>(xw1, dinv, b1, rowptr, edges, W2, xw2, n);
    // K6: conv2 aggregate + relu + MLP head + sigmoid -> out
    k_gather_head<<<2048, 256, 0, stream>>>(xw2, dinv, b2, rowptr, edges,
                                            Wm1, bm1, Wm2, bm2, outp, n);
}